// Round 1
// baseline (129.050 us; speedup 1.0000x reference)
//
#include <hip/hip_runtime.h>

// CenterLoss: out = mean_i ||x_i - centers[labels_i]||^2
// B=16384, D=512, C=4000. One 64-lane wave per row; 8 floats/lane via 2x float4.

#define B_SIZE 16384
#define D_SIZE 512

__global__ __launch_bounds__(256) void center_loss_kernel(
    const float* __restrict__ x,
    const int* __restrict__ labels,
    const float* __restrict__ centers,
    float* __restrict__ out) {

    const int lane = threadIdx.x & 63;
    const int wave = threadIdx.x >> 6;          // 4 waves per block
    const int row  = (blockIdx.x << 2) + wave;  // one row per wave

    float acc = 0.0f;
    if (row < B_SIZE) {
        const int label = labels[row];
        const float4* xp = reinterpret_cast<const float4*>(x + (size_t)row * D_SIZE) + (lane << 1);
        const float4* cp = reinterpret_cast<const float4*>(centers + (size_t)label * D_SIZE) + (lane << 1);
        float4 xa = xp[0];
        float4 xb = xp[1];
        float4 ca = cp[0];
        float4 cb = cp[1];
        float d;
        d = xa.x - ca.x; acc += d * d;
        d = xa.y - ca.y; acc += d * d;
        d = xa.z - ca.z; acc += d * d;
        d = xa.w - ca.w; acc += d * d;
        d = xb.x - cb.x; acc += d * d;
        d = xb.y - cb.y; acc += d * d;
        d = xb.z - cb.z; acc += d * d;
        d = xb.w - cb.w; acc += d * d;
    }

    // wave-level reduction over 64 lanes
    #pragma unroll
    for (int off = 32; off > 0; off >>= 1)
        acc += __shfl_down(acc, off, 64);

    __shared__ float partial[4];
    if (lane == 0) partial[wave] = acc;
    __syncthreads();

    if (threadIdx.x == 0) {
        float s = partial[0] + partial[1] + partial[2] + partial[3];
        atomicAdd(out, s * (1.0f / (float)B_SIZE));
    }
}

extern "C" void kernel_launch(void* const* d_in, const int* in_sizes, int n_in,
                              void* d_out, int out_size, void* d_ws, size_t ws_size,
                              hipStream_t stream) {
    const float* x       = (const float*)d_in[0];
    const int*   labels  = (const int*)d_in[1];
    const float* centers = (const float*)d_in[2];
    float* out = (float*)d_out;

    // d_out is poisoned to 0xAA before every timed replay — zero it (memset node is capture-legal)
    hipMemsetAsync(out, 0, sizeof(float), stream);

    const int blocks = B_SIZE / 4;  // 4 rows (waves) per 256-thread block
    center_loss_kernel<<<blocks, 256, 0, stream>>>(x, labels, centers, out);
}

// Round 2
// 83.329 us; speedup vs baseline: 1.5487x; 1.5487x over previous
//
#include <hip/hip_runtime.h>

// CenterLoss: out = mean_i ||x_i - centers[labels_i]||^2
// B=16384, D=512, C=4000.
// Stage 1: one 64-lane wave per 2 consecutive rows; 8 float4 loads in flight
//          per wave; per-block partial sums to d_ws (NO same-address atomics —
//          4096 serialized atomicAdds were the 56us bottleneck in round 1).
// Stage 2: single block reduces the 2048 partials, writes mean to d_out.

#define B_SIZE 16384
#define D_SIZE 512
#define S1_BLOCKS 2048   // 2048 blocks * 4 waves = 8192 waves * 2 rows = 16384 rows

__global__ __launch_bounds__(256) void center_loss_stage1(
    const float* __restrict__ x,
    const int* __restrict__ labels,
    const float* __restrict__ centers,
    float* __restrict__ partials) {

    const int lane = threadIdx.x & 63;
    const int wave = threadIdx.x >> 6;                 // 4 waves per block
    const int gw   = (blockIdx.x << 2) + wave;         // global wave id
    const int row0 = gw << 1;                          // 2 consecutive rows per wave
    const int row1 = row0 + 1;

    const int l0 = labels[row0];
    const int l1 = labels[row1];

    const float4* x0 = reinterpret_cast<const float4*>(x + (size_t)row0 * D_SIZE) + (lane << 1);
    const float4* x1 = reinterpret_cast<const float4*>(x + (size_t)row1 * D_SIZE) + (lane << 1);
    const float4* c0 = reinterpret_cast<const float4*>(centers + (size_t)l0 * D_SIZE) + (lane << 1);
    const float4* c1 = reinterpret_cast<const float4*>(centers + (size_t)l1 * D_SIZE) + (lane << 1);

    // issue all 8 loads before any use
    float4 xa0 = x0[0], xb0 = x0[1];
    float4 xa1 = x1[0], xb1 = x1[1];
    float4 ca0 = c0[0], cb0 = c0[1];
    float4 ca1 = c1[0], cb1 = c1[1];

    float acc = 0.0f, d;
    d = xa0.x - ca0.x; acc += d * d;
    d = xa0.y - ca0.y; acc += d * d;
    d = xa0.z - ca0.z; acc += d * d;
    d = xa0.w - ca0.w; acc += d * d;
    d = xb0.x - cb0.x; acc += d * d;
    d = xb0.y - cb0.y; acc += d * d;
    d = xb0.z - cb0.z; acc += d * d;
    d = xb0.w - cb0.w; acc += d * d;
    d = xa1.x - ca1.x; acc += d * d;
    d = xa1.y - ca1.y; acc += d * d;
    d = xa1.z - ca1.z; acc += d * d;
    d = xa1.w - ca1.w; acc += d * d;
    d = xb1.x - cb1.x; acc += d * d;
    d = xb1.y - cb1.y; acc += d * d;
    d = xb1.z - cb1.z; acc += d * d;
    d = xb1.w - cb1.w; acc += d * d;

    // wave-level reduction over 64 lanes
    #pragma unroll
    for (int off = 32; off > 0; off >>= 1)
        acc += __shfl_down(acc, off, 64);

    __shared__ float partial[4];
    if (lane == 0) partial[wave] = acc;
    __syncthreads();

    if (threadIdx.x == 0)
        partials[blockIdx.x] = partial[0] + partial[1] + partial[2] + partial[3];
}

__global__ __launch_bounds__(1024) void center_loss_stage2(
    const float* __restrict__ partials,
    float* __restrict__ out) {

    const int t = threadIdx.x;
    float acc = partials[t] + partials[t + 1024];

    const int lane = t & 63;
    const int wave = t >> 6;   // 16 waves

    #pragma unroll
    for (int off = 32; off > 0; off >>= 1)
        acc += __shfl_down(acc, off, 64);

    __shared__ float partial[16];
    if (lane == 0) partial[wave] = acc;
    __syncthreads();

    if (t == 0) {
        float s = 0.0f;
        #pragma unroll
        for (int i = 0; i < 16; ++i) s += partial[i];
        out[0] = s * (1.0f / (float)B_SIZE);
    }
}

extern "C" void kernel_launch(void* const* d_in, const int* in_sizes, int n_in,
                              void* d_out, int out_size, void* d_ws, size_t ws_size,
                              hipStream_t stream) {
    const float* x       = (const float*)d_in[0];
    const int*   labels  = (const int*)d_in[1];
    const float* centers = (const float*)d_in[2];
    float* out      = (float*)d_out;
    float* partials = (float*)d_ws;   // 2048 floats = 8 KB scratch

    center_loss_stage1<<<S1_BLOCKS, 256, 0, stream>>>(x, labels, centers, partials);
    center_loss_stage2<<<1, 1024, 0, stream>>>(partials, out);
}